// Round 2
// baseline (98218.365 us; speedup 1.0000x reference)
//
#include <hip/hip_runtime.h>
#include <cstddef>

#define TSEQ 256
#define NB   128
#define HID  512
#define G3   1536
#define INDIM 768
#define CH   16   // time-chunk for GI precompute

typedef unsigned short bfraw;

__device__ __forceinline__ float bf2f(bfraw u){ return __uint_as_float(((unsigned int)u)<<16); }
__device__ __forceinline__ bfraw f2bf(float f){
  unsigned int u = __float_as_uint(f);
  u += 0x7fffu + ((u>>16)&1u);
  return (bfraw)(u>>16);
}
__device__ __forceinline__ float fsig(float x){
  return __builtin_amdgcn_rcpf(1.0f + __expf(-x));
}
__device__ __forceinline__ float ftanh(float x){
  return 1.0f - 2.0f*__builtin_amdgcn_rcpf(1.0f + __expf(2.0f*x));
}

// ---------------- tiled fp32-accumulate GEMM: C = A(MxK) * op(B) (+bias) -----
// TRANSB: B is (N,K) row-major (x @ W.T); else B is (K,N) row-major.
// TA/TC in {float, bfraw}; B and bias always fp32.
template<bool TRANSB, bool BIAS, typename TA, typename TC>
__global__ __launch_bounds__(256)
void gemm128(const TA* __restrict__ A, const float* __restrict__ B,
             const float* __restrict__ bias, TC* __restrict__ C,
             int K, int lda, int ldb, int ldc)
{
  __shared__ float sA[16][128];
  __shared__ float sB[16][128];
  const int tid = threadIdx.x;
  const int m0 = blockIdx.y * 128;
  const int n0 = blockIdx.x * 128;
  const int ar = tid >> 2;            // 0..63
  const int aq = (tid & 3) << 2;      // 0,4,8,12
  const int br = tid >> 5;            // 0..7
  const int bq = (tid & 31) << 2;     // 0..124
  const int tm = (tid >> 4) << 3;
  const int tn = (tid & 15) << 3;
  float acc[8][8];
  #pragma unroll
  for (int i=0;i<8;++i)
    #pragma unroll
    for (int j=0;j<8;++j) acc[i][j]=0.f;

  for (int k0 = 0; k0 < K; k0 += 16) {
    #pragma unroll
    for (int p=0;p<2;++p){
      int row = ar + p*64;
      float4 v;
      if constexpr (sizeof(TA)==2){
        ushort4 u = *(const ushort4*)(A + (size_t)(m0+row)*lda + k0 + aq);
        v = make_float4(bf2f(u.x), bf2f(u.y), bf2f(u.z), bf2f(u.w));
      } else {
        v = *(const float4*)(A + (size_t)(m0+row)*lda + k0 + aq);
      }
      sA[aq+0][row]=v.x; sA[aq+1][row]=v.y; sA[aq+2][row]=v.z; sA[aq+3][row]=v.w;
    }
    if (TRANSB){
      #pragma unroll
      for (int p=0;p<2;++p){
        int row = ar + p*64;
        float4 v = *(const float4*)(B + (size_t)(n0+row)*ldb + k0 + aq);
        sB[aq+0][row]=v.x; sB[aq+1][row]=v.y; sB[aq+2][row]=v.z; sB[aq+3][row]=v.w;
      }
    } else {
      #pragma unroll
      for (int p=0;p<2;++p){
        int krow = br + p*8;
        float4 v = *(const float4*)(B + (size_t)(k0+krow)*ldb + n0 + bq);
        *(float4*)&sB[krow][bq] = v;
      }
    }
    __syncthreads();
    #pragma unroll
    for (int kk=0;kk<16;++kk){
      float a[8], bb[8];
      *(float4*)&a[0]  = *(const float4*)&sA[kk][tm];
      *(float4*)&a[4]  = *(const float4*)&sA[kk][tm+4];
      *(float4*)&bb[0] = *(const float4*)&sB[kk][tn];
      *(float4*)&bb[4] = *(const float4*)&sB[kk][tn+4];
      #pragma unroll
      for (int i=0;i<8;++i)
        #pragma unroll
        for (int j=0;j<8;++j)
          acc[i][j] = fmaf(a[i], bb[j], acc[i][j]);
    }
    __syncthreads();
  }
  #pragma unroll
  for (int i=0;i<8;++i){
    size_t m = (size_t)(m0 + tm + i);
    #pragma unroll
    for (int j=0;j<8;++j){
      if (BIAS) acc[i][j] += bias[n0+tn+j];
    }
    if constexpr (sizeof(TC)==2){
      #pragma unroll
      for (int j=0;j<8;j+=2){
        unsigned int pk = (unsigned int)f2bf(acc[i][j]) | ((unsigned int)f2bf(acc[i][j+1])<<16);
        *(unsigned int*)((bfraw*)C + m*ldc + n0 + tn + j) = pk;
      }
    } else {
      #pragma unroll
      for (int j=0;j<8;j+=4){
        float4 v; v.x=acc[i][j]; v.y=acc[i][j+1]; v.z=acc[i][j+2]; v.w=acc[i][j+3];
        *(float4*)((float*)C + m*ldc + n0 + tn + j) = v;
      }
    }
  }
}

// b_out[g] = bih[g] + sum_e Wih[g,e]*pb[e]
__global__ void fuse_bias_k(const float* __restrict__ Wih, const float* __restrict__ bih,
                            const float* __restrict__ pb, float* __restrict__ bout)
{
  int g = blockIdx.x*256 + threadIdx.x;
  if (g >= G3) return;
  float acc = bih[g];
  const float* w = Wih + (size_t)g*HID;
  for (int e=0;e<HID;e+=4){
    float4 wv = *(const float4*)(w+e);
    float4 pv = *(const float4*)(pb+e);
    acc += wv.x*pv.x + wv.y*pv.y + wv.z*pv.z + wv.w*pv.w;
  }
  bout[g] = acc;
}

// One GRU time step for both GRUs (blockIdx.z selects p/h).
// grid (16 dchunks, 16 bgroups, 2); block 256 = 8 b x 32 d
__global__ __launch_bounds__(256)
void gru_step_k(const float* __restrict__ GIp_t, const float* __restrict__ GIh_t,
                const float* __restrict__ Whh_p, const float* __restrict__ Whh_h,
                const float* __restrict__ bhh_p, const float* __restrict__ bhh_h,
                const float* __restrict__ hprev_p, const float* __restrict__ hprev_h,
                float* __restrict__ hcur_p, float* __restrict__ hcur_h,
                bfraw* __restrict__ op_t, bfraw* __restrict__ oh_t,
                int is_first)
{
  const int z = blockIdx.z;
  const float* GI  = z ? GIh_t  : GIp_t;
  const float* Whh = z ? Whh_h  : Whh_p;
  const float* bhh = z ? bhh_h  : bhh_p;
  const float* hpv = z ? hprev_h: hprev_p;
  float* hcur      = z ? hcur_h : hcur_p;
  bfraw* obf       = z ? oh_t   : op_t;

  __shared__ float sh[8][HID];
  const int tid = threadIdx.x;
  const int b0 = blockIdx.y * 8;
  #pragma unroll
  for (int i=0;i<16;++i){
    int l = tid + i*256;
    int r = l >> 9, c = l & 511;
    sh[r][c] = is_first ? 1.0f : hpv[(size_t)(b0+r)*HID + c];
  }
  __syncthreads();
  const int dl = tid & 31, bl = tid >> 5;
  const int d = blockIdx.x*32 + dl;
  const int b = b0 + bl;
  float ar = bhh[d], az = bhh[d+HID], an = bhh[d+2*HID];
  const float* wr = Whh + (size_t)d*HID;
  const float* wz = Whh + (size_t)(d+HID)*HID;
  const float* wn = Whh + (size_t)(d+2*HID)*HID;
  const float* hb = sh[bl];
  for (int k=0;k<HID;k+=4){
    float4 h4 = *(const float4*)(hb+k);
    float4 w0 = *(const float4*)(wr+k);
    float4 w1 = *(const float4*)(wz+k);
    float4 w2 = *(const float4*)(wn+k);
    ar += h4.x*w0.x + h4.y*w0.y + h4.z*w0.z + h4.w*w0.w;
    az += h4.x*w1.x + h4.y*w1.y + h4.z*w1.z + h4.w*w1.w;
    an += h4.x*w2.x + h4.y*w2.y + h4.z*w2.z + h4.w*w2.w;
  }
  const float* gi = GI + (size_t)b*G3;
  float r  = fsig(gi[d] + ar);
  float zz = fsig(gi[d+HID] + az);
  float n  = ftanh(gi[d+2*HID] + r*an);
  float hp = hb[d];
  float hv = (1.0f-zz)*n + zz*hp;
  hcur[(size_t)b*HID + d] = hv;
  obf [(size_t)b*HID + d] = f2bf(hv);
}

// cbuf[b,e] = sum_d o_h[t,b,d]*W_t[d,e] + sum_d hm[b,d]*W_m[d,e]
// grid (8 echunks, 32 bgroups); block 256 = 4 b x 64 e
__global__ __launch_bounds__(256)
void wm_k(const float* __restrict__ hm, const bfraw* __restrict__ oh_t,
          const float* __restrict__ W_t, const float* __restrict__ W_m,
          float* __restrict__ cbuf, int is_first)
{
  __shared__ float shm[4][HID];
  __shared__ float sht[4][HID];
  const int tid = threadIdx.x;
  const int b0 = blockIdx.y*4;
  #pragma unroll
  for (int i=0;i<8;++i){
    int l = tid + i*256;
    int r = l >> 9, c = l & 511;
    shm[r][c] = is_first ? 1.0f : hm[(size_t)(b0+r)*HID + c];
    sht[r][c] = bf2f(oh_t[(size_t)(b0+r)*HID + c]);
  }
  __syncthreads();
  const int el = tid & 63, bl = tid >> 6;
  const int e = blockIdx.x*64 + el;
  const int b = b0 + bl;
  float acc = 0.f;
  const float* h = shm[bl];
  const float* x = sht[bl];
  #pragma unroll 4
  for (int dd=0; dd<HID; ++dd){
    acc = fmaf(x[dd], W_t[(size_t)dd*HID + e], acc);
    acc = fmaf(h[dd], W_m[(size_t)dd*HID + e], acc);
  }
  cbuf[(size_t)b*HID + e] = acc;
}

// Per-b block: logits (tanh dot) -> softmax over t -> a_t. grid 128, block 512.
__global__ __launch_bounds__(512)
void att_k(const bfraw* __restrict__ Whs, const bfraw* __restrict__ o_p,
           const float* __restrict__ cbuf, const float* __restrict__ w_e,
           float* __restrict__ a_t)
{
  __shared__ float c_s[HID];
  __shared__ float we_s[HID];
  __shared__ float l_s[TSEQ];
  __shared__ float red[16];
  const int tid = threadIdx.x;
  const int b = blockIdx.x;
  c_s[tid]  = cbuf[(size_t)b*HID + tid];
  we_s[tid] = w_e[tid];
  __syncthreads();
  const int wv = tid >> 6, lane = tid & 63;
  #pragma unroll 1
  for (int i=0;i<32;++i){
    int t = wv*32 + i;
    const bfraw* row = Whs + ((size_t)t*NB + b)*HID;
    float s = 0.f;
    #pragma unroll
    for (int j=0;j<4;++j){
      int d0 = j*128 + lane*2;
      unsigned int u = *(const unsigned int*)(row + d0);
      float v0 = bf2f((bfraw)(u & 0xffffu));
      float v1 = bf2f((bfraw)(u >> 16));
      s += ftanh(v0 + c_s[d0])   * we_s[d0];
      s += ftanh(v1 + c_s[d0+1]) * we_s[d0+1];
    }
    #pragma unroll
    for (int off=32; off; off>>=1) s += __shfl_xor(s, off);
    if (lane==0) l_s[t] = s;
  }
  __syncthreads();
  float v = -1e30f;
  if (tid < TSEQ){
    v = l_s[tid];
    float m = v;
    #pragma unroll
    for (int off=32; off; off>>=1) m = fmaxf(m, __shfl_xor(m, off));
    if (lane==0) red[tid>>6] = m;
  }
  __syncthreads();
  float mx = fmaxf(fmaxf(red[0],red[1]), fmaxf(red[2],red[3]));
  float e = 0.f;
  if (tid < TSEQ){
    e = __expf(v - mx);
    float s = e;
    #pragma unroll
    for (int off=32; off; off>>=1) s += __shfl_xor(s, off);
    if (lane==0) red[8+(tid>>6)] = s;
  }
  __syncthreads();
  float S = red[8]+red[9]+red[10]+red[11];
  if (tid < TSEQ) l_s[tid] = e * __builtin_amdgcn_rcpf(S);
  __syncthreads();
  if (tid < 256){
    const int d0 = tid*2;
    float acc0 = 0.f, acc1 = 0.f;
    #pragma unroll 1
    for (int t=0;t<TSEQ;++t){
      float w = l_s[t];
      unsigned int u = *(const unsigned int*)(o_p + ((size_t)t*NB + b)*HID + d0);
      acc0 = fmaf(w, bf2f((bfraw)(u & 0xffffu)), acc0);
      acc1 = fmaf(w, bf2f((bfraw)(u >> 16)),     acc1);
    }
    a_t[(size_t)b*HID + d0]     = acc0;
    a_t[(size_t)b*HID + d0 + 1] = acc1;
  }
}

// match-GRU cell with in-kernel h_t input gates.
// grid (16 dchunks, 16 bgroups); block 256 = 8 b x 32 d
__global__ __launch_bounds__(256)
void cell_k(const bfraw* __restrict__ oh_t, const float* __restrict__ a_t,
            const float* __restrict__ hm_in, const float* __restrict__ m_Wih,
            const float* __restrict__ m_Whh, const float* __restrict__ m_bih,
            const float* __restrict__ m_bhh, float* __restrict__ hm_out,
            int is_first)
{
  __shared__ float sa[8][HID];
  __shared__ float sx[8][HID];
  __shared__ float sh[8][HID];
  const int tid = threadIdx.x;
  const int b0 = blockIdx.y*8;
  #pragma unroll
  for (int i=0;i<16;++i){
    int l = tid + i*256;
    int r = l >> 9, c = l & 511;
    sa[r][c] = a_t[(size_t)(b0+r)*HID + c];
    sx[r][c] = bf2f(oh_t[(size_t)(b0+r)*HID + c]);
    sh[r][c] = is_first ? 1.0f : hm_in[(size_t)(b0+r)*HID + c];
  }
  __syncthreads();
  const int dl = tid & 31, bl = tid >> 5;
  const int d = blockIdx.x*32 + dl;
  const int b = b0 + bl;
  float gir = m_bih[d], giz = m_bih[d+HID], gin = m_bih[d+2*HID];
  float ghr = m_bhh[d], ghz = m_bhh[d+HID], ghn = m_bhh[d+2*HID];
  const float* wir = m_Wih + (size_t)d*1024;
  const float* wiz = m_Wih + (size_t)(d+HID)*1024;
  const float* win = m_Wih + (size_t)(d+2*HID)*1024;
  const float* whr = m_Whh + (size_t)d*HID;
  const float* whz = m_Whh + (size_t)(d+HID)*HID;
  const float* whn = m_Whh + (size_t)(d+2*HID)*HID;
  const float* av = sa[bl];
  const float* xv = sx[bl];
  const float* hv = sh[bl];
  for (int k=0;k<HID;k+=4){
    float4 a4 = *(const float4*)(av+k);
    float4 x4 = *(const float4*)(xv+k);
    float4 h4 = *(const float4*)(hv+k);
    float4 w;
    w = *(const float4*)(wir+k);     gir += a4.x*w.x + a4.y*w.y + a4.z*w.z + a4.w*w.w;
    w = *(const float4*)(wir+HID+k); gir += x4.x*w.x + x4.y*w.y + x4.z*w.z + x4.w*w.w;
    w = *(const float4*)(wiz+k);     giz += a4.x*w.x + a4.y*w.y + a4.z*w.z + a4.w*w.w;
    w = *(const float4*)(wiz+HID+k); giz += x4.x*w.x + x4.y*w.y + x4.z*w.z + x4.w*w.w;
    w = *(const float4*)(win+k);     gin += a4.x*w.x + a4.y*w.y + a4.z*w.z + a4.w*w.w;
    w = *(const float4*)(win+HID+k); gin += x4.x*w.x + x4.y*w.y + x4.z*w.z + x4.w*w.w;
    w = *(const float4*)(whr+k);     ghr += h4.x*w.x + h4.y*w.y + h4.z*w.z + h4.w*w.w;
    w = *(const float4*)(whz+k);     ghz += h4.x*w.x + h4.y*w.y + h4.z*w.z + h4.w*w.w;
    w = *(const float4*)(whn+k);     ghn += h4.x*w.x + h4.y*w.y + h4.z*w.z + h4.w*w.w;
  }
  float r  = fsig(gir + ghr);
  float zz = fsig(giz + ghz);
  float n  = ftanh(gin + r*ghn);
  float hp = hv[d];
  hm_out[(size_t)b*HID + d] = (1.0f-zz)*n + zz*hp;
}

__global__ void out_k(const float* __restrict__ hm, const float* __restrict__ oW,
                      const float* __restrict__ ob, float* __restrict__ out)
{
  int tid = threadIdx.x; // 384
  if (tid >= NB*3) return;
  int b = tid / 3, c = tid % 3;
  float acc = ob[c];
  const float* h = hm + (size_t)b*HID;
  const float* w = oW + (size_t)c*HID;
  for (int d2=0; d2<HID; ++d2) acc = fmaf(h[d2], w[d2], acc);
  out[tid] = fmaxf(acc, 0.f);
}

extern "C" void kernel_launch(void* const* d_in, const int* in_sizes, int n_in,
                              void* d_out, int out_size, void* d_ws, size_t ws_size,
                              hipStream_t stream)
{
  const float* Ep    = (const float*)d_in[0];
  const float* Eh    = (const float*)d_in[1];
  const float* p_W   = (const float*)d_in[2];
  const float* p_b   = (const float*)d_in[3];
  const float* h_W   = (const float*)d_in[4];
  const float* h_b   = (const float*)d_in[5];
  const float* pgWih = (const float*)d_in[6];
  const float* pgWhh = (const float*)d_in[7];
  const float* pgbih = (const float*)d_in[8];
  const float* pgbhh = (const float*)d_in[9];
  const float* hgWih = (const float*)d_in[10];
  const float* hgWhh = (const float*)d_in[11];
  const float* hgbih = (const float*)d_in[12];
  const float* hgbhh = (const float*)d_in[13];
  const float* W_s   = (const float*)d_in[14];
  const float* W_t   = (const float*)d_in[15];
  const float* w_e   = (const float*)d_in[16];
  const float* W_m   = (const float*)d_in[17];
  const float* mWih  = (const float*)d_in[18];
  const float* mWhh  = (const float*)d_in[19];
  const float* mbih  = (const float*)d_in[20];
  const float* mbhh  = (const float*)d_in[21];
  const float* outW  = (const float*)d_in[22];
  const float* outb  = (const float*)d_in[23];

  const size_t SZ_O   = (size_t)TSEQ*NB*HID;            // 16,777,216 elems
  const size_t OB     = SZ_O*sizeof(bfraw);             // 33,554,432 B
  const size_t CHUNKF = (size_t)CH*NB*G3;               // 3,145,728 floats
  const size_t WFF    = (size_t)G3*INDIM;               // 1,179,648 floats
  const size_t RB     = (2*CHUNKF + 2*WFF + 2*G3)*sizeof(float); // 34,615,296 B
  const size_t SMALLB = 8*(size_t)NB*HID*sizeof(float); // 2,097,152 B
  const size_t needed = 2*OB + RB + SMALLB;             // ~103.8 MB
  if (ws_size < needed) return;

  char* base = (char*)d_ws;
  bfraw* o_p_bf = (bfraw*)base;
  bfraw* o_h_bf = (bfraw*)(base + OB);
  char*  Rb     = base + 2*OB;
  float* Rf     = (float*)Rb;
  float* GIp_c  = Rf;
  float* GIh_c  = Rf + CHUNKF;
  float* Wfp    = Rf + 2*CHUNKF;
  float* Wfh    = Wfp + WFF;
  float* bfp    = Wfh + WFF;
  float* bfh    = bfp + G3;
  bfraw* Whs_bf = (bfraw*)Rb;              // overlays chunk region after phase B
  float* smallf = (float*)(base + 2*OB + RB);
  float* hsp0 = smallf;
  float* hsp1 = hsp0 + (size_t)NB*HID;
  float* hsh0 = hsp1 + (size_t)NB*HID;
  float* hsh1 = hsh0 + (size_t)NB*HID;
  float* hm0  = hsh1 + (size_t)NB*HID;
  float* hm1  = hm0  + (size_t)NB*HID;
  float* atb  = hm1  + (size_t)NB*HID;
  float* cbuf = atb  + (size_t)NB*HID;

  dim3 blk(256);

  // Phase A: fused input-gate weights Wf = Wih @ xW  (G3 x INDIM) and biases
  gemm128<false,false,float,float><<<dim3(INDIM/128, G3/128), blk, 0, stream>>>(pgWih, p_W, nullptr, Wfp, HID, HID, INDIM, INDIM);
  gemm128<false,false,float,float><<<dim3(INDIM/128, G3/128), blk, 0, stream>>>(hgWih, h_W, nullptr, Wfh, HID, HID, INDIM, INDIM);
  fuse_bias_k<<<dim3(G3/256), blk, 0, stream>>>(pgWih, pgbih, p_b, bfp);
  fuse_bias_k<<<dim3(G3/256), blk, 0, stream>>>(hgWih, hgbih, h_b, bfh);

  // Phase B: chunked GI precompute + both GRU scans
  for (int c = 0; c < TSEQ/CH; ++c){
    gemm128<true,true,float,float><<<dim3(G3/128, (CH*NB)/128), blk, 0, stream>>>(
      Ep + (size_t)c*CH*NB*INDIM, Wfp, bfp, GIp_c, INDIM, INDIM, INDIM, G3);
    gemm128<true,true,float,float><<<dim3(G3/128, (CH*NB)/128), blk, 0, stream>>>(
      Eh + (size_t)c*CH*NB*INDIM, Wfh, bfh, GIh_c, INDIM, INDIM, INDIM, G3);
    for (int tt = 0; tt < CH; ++tt){
      int t = c*CH + tt;
      const float* hp_p = (t&1) ? hsp1 : hsp0;
      const float* hp_h = (t&1) ? hsh1 : hsh0;
      float* hc_p = (t&1) ? hsp0 : hsp1;
      float* hc_h = (t&1) ? hsh0 : hsh1;
      gru_step_k<<<dim3(16,16,2), blk, 0, stream>>>(
        GIp_c + (size_t)tt*NB*G3, GIh_c + (size_t)tt*NB*G3,
        pgWhh, hgWhh, pgbhh, hgbhh,
        hp_p, hp_h, hc_p, hc_h,
        o_p_bf + (size_t)t*NB*HID, o_h_bf + (size_t)t*NB*HID,
        (t==0)?1:0);
    }
  }

  // Phase C: Whs = o_p @ W_s  (bf16 in, fp32 acc, bf16 out) — overlays chunk region
  gemm128<false,false,bfraw,bfraw><<<dim3(HID/128, (TSEQ*NB)/128), blk, 0, stream>>>(
    o_p_bf, W_s, nullptr, Whs_bf, HID, HID, HID, HID);

  // Phase D: attention-match scan
  for (int t = 0; t < TSEQ; ++t){
    float* hmi = (t&1) ? hm1 : hm0;
    float* hmo = (t&1) ? hm0 : hm1;
    int isf = (t==0)?1:0;
    const bfraw* oh_t = o_h_bf + (size_t)t*NB*HID;
    wm_k<<<dim3(8,32), blk, 0, stream>>>(hmi, oh_t, W_t, W_m, cbuf, isf);
    att_k<<<dim3(128), dim3(512), 0, stream>>>(Whs_bf, o_p_bf, cbuf, w_e, atb);
    cell_k<<<dim3(16,16), blk, 0, stream>>>(oh_t, atb, hmi, mWih, mWhh, mbih, mbhh, hmo, isf);
  }

  // Phase E: output head (h_star is hm0 after 256 steps)
  out_k<<<dim3(1), dim3(384), 0, stream>>>(hm0, outW, outb, (float*)d_out);
}